// Round 8
// baseline (134.176 us; speedup 1.0000x reference)
//
#include <hip/hip_runtime.h>

typedef unsigned short ushort_t;
typedef __attribute__((ext_vector_type(8))) short short8;
typedef __attribute__((ext_vector_type(4))) float float4v;

#define Bn 32
#define Nn 2048
#define Cn 8
#define Fn 128
#define On 128
#define RPB 256                  // rows per block
#define NBLK ((Bn * Nn) / RPB)   // 256 blocks = 1 per CU
#define NBF_OFF 131072           // byte offset of bf16 nodes in workspace

// float -> bf16 bits, round-to-nearest-even
__device__ __forceinline__ ushort_t f2bf(float x) {
  unsigned u = __float_as_uint(x);
  u += 0x7fffu + ((u >> 16) & 1u);
  return (ushort_t)(u >> 16);
}

// HW packed f32->bf16 (RNE), 2 elements / instr.
__device__ __forceinline__ unsigned cvt_pk_bf16(float lo, float hi) {
  unsigned r;
  asm("v_cvt_pk_bf16_f32 %0, %1, %2" : "=v"(r) : "v"(lo), "v"(hi));
  return r;
}

// Fused prep: (a) nodes f32 -> bf16 workspace copy; (b) w_t/w_r/w_l packed
// into MFMA B-fragment order (layout identical to all prior rounds:
// fragment q, chunk ks: element ((q*12+ks)*64+lane)*8+j = W[k][col],
// col = q*16+(lane&15), k = (lane>>4)*8 + ks*32 + j).
__global__ void prep_kernel(const float* __restrict__ nodes,
                            const float* __restrict__ w_t,
                            const float* __restrict__ w_l,
                            const float* __restrict__ w_r,
                            ushort_t* __restrict__ wsw,
                            ushort_t* __restrict__ nbf) {
  if (blockIdx.x < 4096) {
    // nodes: 8.39M floats, 8 per thread
    const int t = blockIdx.x * 256 + threadIdx.x;
    const float4v* s = (const float4v*)(nodes + (size_t)t * 8);
    float4v a = s[0], b = s[1];
    short8 d;
    unsigned* du = (unsigned*)&d;
    du[0] = cvt_pk_bf16(a.x, a.y);
    du[1] = cvt_pk_bf16(a.z, a.w);
    du[2] = cvt_pk_bf16(b.x, b.y);
    du[3] = cvt_pk_bf16(b.z, b.w);
    *(short8*)(nbf + (size_t)t * 8) = d;
  } else {
    const int t = (blockIdx.x - 4096) * 256 + threadIdx.x;  // 0..6143
    if (t >= 6144) return;
    const int lane = t & 63;
    const int r = t >> 6;
    const int ks = r % 12;
    const int q = r / 12;
    const int col = q * 16 + (lane & 15);
    const int kbase = ((lane >> 4) * 8) + ks * 32;
    ushort_t* dst = wsw + (size_t)t * 8;
#pragma unroll
    for (int j = 0; j < 8; ++j) {
      const int k = kbase + j;
      const float* src = (k < Fn) ? w_t : (k < 2 * Fn) ? w_r : w_l;
      const int f = k & (Fn - 1);
      dst[j] = f2bf(src[f * On + col]);
    }
  }
}

// Gather one tile's A-fragments for the current f-slice from LDS.
// Lane (l15,quad): row = tile*16+l15, f-local = quad*8..+8.
// aft = self (raw bf16 passthrough), afr = sum cr*child, afl = msum - afr.
__device__ __forceinline__ void gather_tile(const ushort_t* __restrict__ nds,
                                            int selfad, const int (&cad)[Cn],
                                            const float (&crv)[Cn],
                                            const float (&mv)[Cn],
                                            short8& aft, short8& afr,
                                            short8& afl) {
  aft = *(const short8*)(nds + selfad);
  float rr[8] = {0, 0, 0, 0, 0, 0, 0, 0};
  float ms[8] = {0, 0, 0, 0, 0, 0, 0, 0};
#pragma unroll
  for (int c = 0; c < Cn; ++c) {
    const short8 cv = *(const short8*)(nds + cad[c]);
    const unsigned* u = (const unsigned*)&cv;
    float f[8];
#pragma unroll
    for (int p = 0; p < 4; ++p) {
      f[2 * p]     = __uint_as_float(u[p] << 16);          // low bf16
      f[2 * p + 1] = __uint_as_float(u[p] & 0xffff0000u);  // high bf16
    }
    const float cr = crv[c], m = mv[c];
#pragma unroll
    for (int j = 0; j < 8; ++j) {
      rr[j] += cr * f[j];
      ms[j] += m * f[j];
    }
  }
  unsigned* pr = (unsigned*)&afr;
  unsigned* pl = (unsigned*)&afl;
#pragma unroll
  for (int p = 0; p < 4; ++p) {
    pr[p] = cvt_pk_bf16(rr[2 * p], rr[2 * p + 1]);
    pl[p] = cvt_pk_bf16(ms[2 * p] - rr[2 * p], ms[2 * p + 1] - rr[2 * p + 1]);
  }
}

// 512 threads / 8 waves, 1 block per CU (LDS 128 KiB). Per phase: stage the
// whole batch's 32-f bf16 slice into LDS (coalesced), then gather children
// from LDS (no L2 random access, no MSHR limit) and MFMA-accumulate the
// K=384 GEMM across the 4 phases in registers.
__global__ __launch_bounds__(512, 2)
void tree_conv_kernel(const ushort_t* __restrict__ nbf,
                      const int* __restrict__ children,
                      const ushort_t* __restrict__ wsw,
                      const float* __restrict__ bias,
                      float* __restrict__ out) {
  __shared__ __align__(16) ushort_t nds[Nn * 32];  // 2048 rows x 32 bf16 = 128 KiB

  const int tid = threadIdx.x;
  // 256 blocks: XCD x owns 32 consecutive sblk = 4 batches (2 MiB bf16 -> L2-fit)
  const int sblk = ((blockIdx.x & 7) << 5) | (blockIdx.x >> 3);
  const int batch = sblk >> 3;
  const int row0 = (sblk & 7) * RPB;

  const int ln = tid & 63;
  const int wv = tid >> 6;  // 0..7; wave owns tiles {2wv, 2wv+1} x all 8 col-tiles
  const int l15 = ln & 15;
  const int quad = ln >> 4;

  const ushort_t* nb = nbf + (size_t)batch * (Nn * Fn);

  // ---- persistent per-tile state: LDS gather addresses + coefficients ----
  int cad[2][Cn], selfad[2];
  float crv[2][Cn], mv[2][Cn];
#pragma unroll
  for (int t2 = 0; t2 < 2; ++t2) {
    const int brow = row0 + (wv * 2 + t2) * 16 + l15;  // row within batch
    const int4* p4 = (const int4*)(children + ((size_t)batch * Nn + brow) * Cn);
    const int4 a = p4[0], b = p4[1];
    const int id[Cn] = {a.x, a.y, a.z, a.w, b.x, b.y, b.z, b.w};
    int ns = 0;
#pragma unroll
    for (int c = 0; c < Cn; ++c) ns += (id[c] != 0) ? 1 : 0;
    const bool single = (ns == 1);
    const float rden = (ns > 1) ? (1.0f / (float)(ns - 1)) : 0.0f;
#pragma unroll
    for (int c = 0; c < Cn; ++c) {
      const float m = (id[c] != 0) ? 1.0f : 0.0f;
      const float cr = single ? ((c == 0) ? 0.5f : 0.0f) : ((float)c * rden);
      crv[t2][c] = cr * m;
      mv[t2][c] = m;
      const int ix = id[c] & (Nn - 1);  // fault-proof clamp (poisoned replays)
      // XOR-swizzled 16B chunk: slot = quad ^ (row&3) (write side matches)
      cad[t2][c] = ix * 32 + ((quad ^ (ix & 3)) * 8);
    }
    selfad[t2] = brow * 32 + ((quad ^ (brow & 3)) * 8);
  }
  float bb[8];
#pragma unroll
  for (int q = 0; q < 8; ++q) bb[q] = bias[q * 16 + l15];

  float4v acc[2][8];
#pragma unroll
  for (int t2 = 0; t2 < 2; ++t2)
#pragma unroll
    for (int q = 0; q < 8; ++q) acc[t2][q] = (float4v){0.f, 0.f, 0.f, 0.f};

  const short8* wb = (const short8*)wsw + ln;

  for (int ph = 0; ph < 4; ++ph) {
    if (ph) __syncthreads();  // previous slice fully consumed

    // ---- stage f-slice [ph*32, ph*32+32) of all 2048 rows (reg-staged,
    // swizzled ds_write; src linear & coalesced: 1 KiB per wave-instr) ----
    {
      short8 tmp[16];
#pragma unroll
      for (int i = 0; i < 16; ++i) {
        const int idx = i * 512 + tid;
        const int r = idx >> 2;
        const int ch = idx & 3;
        tmp[i] = *(const short8*)(nb + (size_t)r * Fn + ph * 32 + ch * 8);
      }
#pragma unroll
      for (int i = 0; i < 16; ++i) {
        const int idx = i * 512 + tid;
        const int r = idx >> 2;
        const int ch = idx & 3;
        *(short8*)(nds + r * 32 + ((ch ^ (r & 3)) * 8)) = tmp[i];
      }
    }
    __syncthreads();  // slice visible to all waves

    // ---- gather + aggregate both tiles' A-fragments from LDS ----
    short8 af[2][3];
#pragma unroll
    for (int t2 = 0; t2 < 2; ++t2)
      gather_tile(nds, selfad[t2], cad[t2], crv[t2], mv[t2],
                  af[t2][0], af[t2][1], af[t2][2]);

    // ---- MFMA: 3 kinds x 8 col-tiles; B-frag chunk ks = kind*4 + ph.
    // All 8 waves read identical frags -> L1 broadcast. ----
#pragma unroll
    for (int kind = 0; kind < 3; ++kind) {
#pragma unroll
      for (int q = 0; q < 8; ++q) {
        const short8 b = wb[(q * 12 + kind * 4 + ph) * 64];
        acc[0][q] = __builtin_amdgcn_mfma_f32_16x16x32_bf16(af[0][kind], b,
                                                            acc[0][q], 0, 0, 0);
        acc[1][q] = __builtin_amdgcn_mfma_f32_16x16x32_bf16(af[1][kind], b,
                                                            acc[1][q], 0, 0, 0);
      }
    }
  }

  // ---- epilogue: bias + relu + store (same C-layout as proven kernel) ----
#pragma unroll
  for (int t2 = 0; t2 < 2; ++t2) {
    const int grow0 = batch * Nn + row0 + (wv * 2 + t2) * 16 + quad * 4;
#pragma unroll
    for (int q = 0; q < 8; ++q) {
#pragma unroll
      for (int r2 = 0; r2 < 4; ++r2) {
        out[(size_t)(grow0 + r2) * On + q * 16 + l15] =
            fmaxf(acc[t2][q][r2] + bb[q], 0.f);
      }
    }
  }
}

extern "C" void kernel_launch(void* const* d_in, const int* in_sizes, int n_in,
                              void* d_out, int out_size, void* d_ws, size_t ws_size,
                              hipStream_t stream) {
  const float* nodes = (const float*)d_in[0];
  const int* children = (const int*)d_in[1];
  const float* w_t = (const float*)d_in[2];
  const float* w_l = (const float*)d_in[3];
  const float* w_r = (const float*)d_in[4];
  const float* bias = (const float*)d_in[5];
  float* out = (float*)d_out;
  ushort_t* wsw = (ushort_t*)d_ws;                          // 96 KiB B-fragments
  ushort_t* nbf = (ushort_t*)((char*)d_ws + NBF_OFF);       // 16 MiB bf16 nodes

  prep_kernel<<<4120, 256, 0, stream>>>(nodes, w_t, w_l, w_r, wsw, nbf);
  tree_conv_kernel<<<NBLK, 512, 0, stream>>>(nbf, children, wsw, bias, out);
}

// Round 9
// 111.480 us; speedup vs baseline: 1.2036x; 1.2036x over previous
//
#include <hip/hip_runtime.h>

typedef unsigned short ushort_t;
typedef __attribute__((ext_vector_type(8))) short short8;
typedef __attribute__((ext_vector_type(4))) short short4v;
typedef __attribute__((ext_vector_type(4))) float float4v;
typedef __attribute__((ext_vector_type(2))) unsigned int uint2v;

#define Bn 32
#define Nn 2048
#define Cn 8
#define Fn 128
#define On 128
#define Kn 384   // 3*F
#define MT 64    // rows per workgroup (B-stream amortized 4x, proven R2)
#define LDSK 392 // Kn + 8 pad (shorts); row stride 784 B
#define NBLK ((Bn * Nn) / MT)  // 1024 blocks
#define NBF_OFF 131072         // byte offset of bf16 nodes in workspace

// float -> bf16 bits, round-to-nearest-even (prep only)
__device__ __forceinline__ ushort_t f2bf(float x) {
  unsigned u = __float_as_uint(x);
  u += 0x7fffu + ((u >> 16) & 1u);
  return (ushort_t)(u >> 16);
}

// HW packed f32->bf16 (RNE), 2 elements / instr.
__device__ __forceinline__ unsigned cvt_pk_bf16(float lo, float hi) {
  unsigned r;
  asm("v_cvt_pk_bf16_f32 %0, %1, %2" : "=v"(r) : "v"(lo), "v"(hi));
  return r;
}

// Fused prep (validated R8): (a) nodes f32 -> bf16 copy; (b) w_t/w_r/w_l
// packed into MFMA B-fragment order (layout identical to all rounds).
__global__ void prep_kernel(const float* __restrict__ nodes,
                            const float* __restrict__ w_t,
                            const float* __restrict__ w_l,
                            const float* __restrict__ w_r,
                            ushort_t* __restrict__ wsw,
                            ushort_t* __restrict__ nbf) {
  if (blockIdx.x < 4096) {
    const int t = blockIdx.x * 256 + threadIdx.x;  // one 8-float chunk
    const float4v* s = (const float4v*)(nodes + (size_t)t * 8);
    float4v a = s[0], b = s[1];
    short8 d;
    unsigned* du = (unsigned*)&d;
    du[0] = cvt_pk_bf16(a.x, a.y);
    du[1] = cvt_pk_bf16(a.z, a.w);
    du[2] = cvt_pk_bf16(b.x, b.y);
    du[3] = cvt_pk_bf16(b.z, b.w);
    *(short8*)(nbf + (size_t)t * 8) = d;
  } else {
    const int t = (blockIdx.x - 4096) * 256 + threadIdx.x;  // 0..6143
    if (t >= 6144) return;
    const int lane = t & 63;
    const int r = t >> 6;
    const int ks = r % 12;
    const int q = r / 12;
    const int col = q * 16 + (lane & 15);
    const int kbase = ((lane >> 4) * 8) + ks * 32;
    ushort_t* dst = wsw + (size_t)t * 8;
#pragma unroll
    for (int j = 0; j < 8; ++j) {
      const int k = kbase + j;
      const float* src = (k < Fn) ? w_t : (k < 2 * Fn) ? w_r : w_l;
      const int f = k & (Fn - 1);
      dst[j] = f2bf(src[f * On + col]);
    }
  }
}

__device__ __forceinline__ void unpack4(short4v v, float (&f)[4]) {
  const unsigned* u = (const unsigned*)&v;
  f[0] = __uint_as_float(u[0] << 16);
  f[1] = __uint_as_float(u[0] & 0xffff0000u);
  f[2] = __uint_as_float(u[1] << 16);
  f[3] = __uint_as_float(u[1] & 0xffff0000u);
}

// Issue the 9 gather loads (self + 8 children) for global row g from the
// bf16 node array. 32-lane group, short4 (8 B)/lane: 32 x 8 B = 256 B per
// instr = one full bf16 row, fully coalesced. HALF of R2's gather bytes.
__device__ __forceinline__ void issue_row(const ushort_t* __restrict__ nbf,
                                          int g, int ln,
                                          const int4& a, const int4& b,
                                          short4v (&dst)[9]) {
  const int base_row = g & ~(Nn - 1);  // b * Nn
  const short4v* np = (const short4v*)nbf;  // 32 chunks per row
  dst[0] = np[(size_t)g * 32 + ln];         // self
  const int id[Cn] = {a.x, a.y, a.z, a.w, b.x, b.y, b.z, b.w};
#pragma unroll
  for (int c = 0; c < Cn; ++c) {
    // fault-proofing clamp: a replay with poisoned `children` cannot fault.
    const int ix = id[c] & (Nn - 1);
    dst[1 + c] = np[(size_t)(base_row + ix) * 32 + ln];
  }
}

// Consume one row: unpack children bf16->f32, coefficients, rr, ll=msum-rr,
// pack to bf16, write LDS agg row. Self is a raw passthrough (bf16 already;
// RNE(bf16(x)) == bf16(x), numerically identical to R2).
__device__ __forceinline__ void compute_row(ushort_t* __restrict__ agg,
                                            int row, int ln,
                                            const int4& a, const int4& b,
                                            const short4v (&v)[9]) {
  const int id[Cn] = {a.x, a.y, a.z, a.w, b.x, b.y, b.z, b.w};
  int ns = 0;
#pragma unroll
  for (int c = 0; c < Cn; ++c) ns += (id[c] != 0) ? 1 : 0;
  const bool single = (ns == 1);
  const float rden = (ns > 1) ? (1.0f / (float)(ns - 1)) : 0.0f;

  float rr[4] = {0.f, 0.f, 0.f, 0.f};
  float ms[4] = {0.f, 0.f, 0.f, 0.f};
#pragma unroll
  for (int c = 0; c < Cn; ++c) {
    const float m = (id[c] != 0) ? 1.0f : 0.0f;
    float cr = single ? ((c == 0) ? 0.5f : 0.0f) : ((float)c * rden);
    cr *= m;
    float f[4];
    unpack4(v[1 + c], f);
#pragma unroll
    for (int j = 0; j < 4; ++j) {
      rr[j] += cr * f[j];
      ms[j] += m * f[j];
    }
  }

  ushort_t* arow = agg + row * LDSK + ln * 4;
  *(short4v*)(arow) = v[0];  // self passthrough
  uint2v wr, wl;
  wr.x = cvt_pk_bf16(rr[0], rr[1]);
  wr.y = cvt_pk_bf16(rr[2], rr[3]);
  wl.x = cvt_pk_bf16(ms[0] - rr[0], ms[1] - rr[1]);
  wl.y = cvt_pk_bf16(ms[2] - rr[2], ms[3] - rr[3]);
  *(uint2v*)(arow + Fn)     = wr;
  *(uint2v*)(arow + 2 * Fn) = wl;
}

// R2's proven skeleton, unchanged except bf16 gathers.
__global__ __launch_bounds__(256, 3)
void tree_conv_kernel(const ushort_t* __restrict__ nbf,
                      const int* __restrict__ children,
                      const ushort_t* __restrict__ wsw,
                      const float* __restrict__ bias,
                      float* __restrict__ out) {
  __shared__ __align__(16) ushort_t agg[MT * LDSK];  // 64 rows x 784 B = 49 KiB

  const int tid = threadIdx.x;

  // XCD-locality swizzle (grid 1024): XCD k owns batches 4k..4k+3
  // (2 MiB of bf16 nodes -> comfortable fit in the XCD's 4 MiB L2).
  const int sb = ((blockIdx.x & 7) << 7) | (blockIdx.x >> 3);

  // ---------------- Phase A: 2-deep register-pipelined gather ---------------
  // 8 groups of 32 lanes; group owns rows {it*8+grp}, it = 0..7.
  {
    const int grp = tid >> 5;  // 0..7
    const int ln = tid & 31;   // lane owns bf16 features [ln*4, ln*4+4)
    const int g0 = sb * MT + grp;  // global row for it: g0 + it*8

    int4 ca[8], cb[8];
#define LDCH(i)                                                              \
  {                                                                          \
    const int4* chv = (const int4*)(children + (size_t)(g0 + (i)*8) * Cn);   \
    ca[i] = chv[0];                                                          \
    cb[i] = chv[1];                                                          \
  }
    LDCH(0) LDCH(1) LDCH(2)

    short4v v0[9], v1[9];
    issue_row(nbf, g0 + 0 * 8, ln, ca[0], cb[0], v0);
    LDCH(3)
    issue_row(nbf, g0 + 1 * 8, ln, ca[1], cb[1], v1);
    compute_row(agg, 0 * 8 + grp, ln, ca[0], cb[0], v0);
    LDCH(4)
    issue_row(nbf, g0 + 2 * 8, ln, ca[2], cb[2], v0);
    compute_row(agg, 1 * 8 + grp, ln, ca[1], cb[1], v1);
    LDCH(5)
    issue_row(nbf, g0 + 3 * 8, ln, ca[3], cb[3], v1);
    compute_row(agg, 2 * 8 + grp, ln, ca[2], cb[2], v0);
    LDCH(6)
    issue_row(nbf, g0 + 4 * 8, ln, ca[4], cb[4], v0);
    compute_row(agg, 3 * 8 + grp, ln, ca[3], cb[3], v1);
    LDCH(7)
    issue_row(nbf, g0 + 5 * 8, ln, ca[5], cb[5], v1);
    compute_row(agg, 4 * 8 + grp, ln, ca[4], cb[4], v0);
    issue_row(nbf, g0 + 6 * 8, ln, ca[6], cb[6], v0);
    compute_row(agg, 5 * 8 + grp, ln, ca[5], cb[5], v1);
    issue_row(nbf, g0 + 7 * 8, ln, ca[7], cb[7], v1);
    compute_row(agg, 6 * 8 + grp, ln, ca[6], cb[6], v0);
    compute_row(agg, 7 * 8 + grp, ln, ca[7], cb[7], v1);
#undef LDCH
  }

  // ---------------- Phase B: MFMA; each wave = 2 col-tiles x 4 M-tiles ------
  // (identical to R2: B-fragments loaded once per wave, 96 KB per block)
  const int lane = tid & 63;
  const int wave = tid >> 6;  // 0..3
  const int l15 = lane & 15;
  const int quad = lane >> 4;
  const int ct0 = wave * 2, ct1 = wave * 2 + 1;

  short8 bf0[12], bf1[12];
  const short8* bbase = (const short8*)wsw + lane;
#pragma unroll
  for (int ks = 0; ks < 12; ++ks) bf0[ks] = bbase[(ct0 * 12 + ks) * 64];
#pragma unroll
  for (int ks = 0; ks < 12; ++ks) bf1[ks] = bbase[(ct1 * 12 + ks) * 64];
  const float bb0 = bias[ct0 * 16 + l15];
  const float bb1 = bias[ct1 * 16 + l15];

  asm volatile("s_waitcnt lgkmcnt(0)" ::: "memory");
  __builtin_amdgcn_s_barrier();
  asm volatile("" ::: "memory");

#pragma unroll
  for (int mt = 0; mt < 4; ++mt) {
    const ushort_t* ar = agg + (mt * 16 + l15) * LDSK + quad * 8;
    short8 af[12];
#pragma unroll
    for (int ks = 0; ks < 12; ++ks) af[ks] = *(const short8*)(ar + ks * 32);

    float4v acc0 = {0.f, 0.f, 0.f, 0.f};
    float4v acc1 = {0.f, 0.f, 0.f, 0.f};
#pragma unroll
    for (int ks = 0; ks < 12; ++ks)
      acc0 = __builtin_amdgcn_mfma_f32_16x16x32_bf16(af[ks], bf0[ks], acc0, 0, 0, 0);
#pragma unroll
    for (int ks = 0; ks < 12; ++ks)
      acc1 = __builtin_amdgcn_mfma_f32_16x16x32_bf16(af[ks], bf1[ks], acc1, 0, 0, 0);

    const int grow0 = sb * MT + mt * 16 + quad * 4;
#pragma unroll
    for (int r2 = 0; r2 < 4; ++r2) {
      const size_t ro = (size_t)(grow0 + r2) * On;
      out[ro + ct0 * 16 + l15] = fmaxf(acc0[r2] + bb0, 0.f);
      out[ro + ct1 * 16 + l15] = fmaxf(acc1[r2] + bb1, 0.f);
    }
  }
}

extern "C" void kernel_launch(void* const* d_in, const int* in_sizes, int n_in,
                              void* d_out, int out_size, void* d_ws, size_t ws_size,
                              hipStream_t stream) {
  const float* nodes = (const float*)d_in[0];
  const int* children = (const int*)d_in[1];
  const float* w_t = (const float*)d_in[2];
  const float* w_l = (const float*)d_in[3];
  const float* w_r = (const float*)d_in[4];
  const float* bias = (const float*)d_in[5];
  float* out = (float*)d_out;
  ushort_t* wsw = (ushort_t*)d_ws;                     // 96 KiB B-fragments
  ushort_t* nbf = (ushort_t*)((char*)d_ws + NBF_OFF);  // 16 MiB bf16 nodes

  prep_kernel<<<4120, 256, 0, stream>>>(nodes, w_t, w_l, w_r, wsw, nbf);
  tree_conv_kernel<<<NBLK, 256, 0, stream>>>(nbf, children, wsw, bias, out);
}